// Round 1
// baseline (166.952 us; speedup 1.0000x reference)
//
#include <hip/hip_runtime.h>

// Problem constants (from setup_inputs): B=8, H=W=128, Cin=128, Cout=256,
// KSIZE=3, STRIDE=2, PAD=1, DIL=1  ->  OH=OW=64.
// Implicit GEMM: M = 8*64*64 = 32768, N = 256, K = 9*128 = 1152.
// d_out layout (all float32): out_feats[32768*256] | out_coords[32768*3] | alpha[1]

#define OUT_FEATS_ELEMS (32768 * 256)
#define OUT_COORDS_OFF  OUT_FEATS_ELEMS
#define ALPHA_OFF       (OUT_FEATS_ELEMS + 32768 * 3)

typedef __bf16 v8bf __attribute__((ext_vector_type(8)));
typedef float  v4f  __attribute__((ext_vector_type(4)));

__device__ __forceinline__ unsigned short f2bf(float f) {
    union { float f; unsigned u; } v; v.f = f;
    unsigned r = (v.u + 0x7fffu + ((v.u >> 16) & 1u)) >> 16;
    return (unsigned short)r;
}

// ---- prepass 1: feats fp32 -> bf16 copy in ws (16777216 elems) ----
__global__ void conv_feats_kernel(const float4* __restrict__ f, ushort4* __restrict__ o) {
    int i = blockIdx.x * 256 + threadIdx.x;      // exactly 4194304 threads
    float4 v = f[i];
    ushort4 r;
    r.x = f2bf(v.x); r.y = f2bf(v.y); r.z = f2bf(v.z); r.w = f2bf(v.w);
    o[i] = r;
}

// ---- prepass 2: weight (9,128,256) fp32 -> Bt[n=256][kc=1152] bf16 (transposed) ----
__global__ void conv_wt_kernel(const float* __restrict__ w, unsigned short* __restrict__ bt) {
    int k = blockIdx.x;       // 0..1151  (kc = tap*128 + c)
    int n = threadIdx.x;      // 0..255
    bt[n * 1152 + k] = f2bf(w[k * 256 + n]);
}

// ---- coords + alpha ----
__global__ void coords_alpha_kernel(float* __restrict__ out, const float* __restrict__ alpha) {
    int i = blockIdx.x * 256 + threadIdx.x;      // 0..32767
    int b  = i >> 12;
    int iy = (i >> 6) & 63;
    int ix = i & 63;
    float* c = out + OUT_COORDS_OFF + (size_t)i * 3;
    c[0] = (float)b; c[1] = (float)iy; c[2] = (float)ix;
    if (i == 0) out[ALPHA_OFF] = alpha[0];
}

// ---- main implicit-GEMM conv: 128x128 tile, BK=32, 4 waves of 4x4 mfma_16x16x32_bf16 ----
__global__ __launch_bounds__(256, 2) void gemm_conv_kernel(
    const unsigned short* __restrict__ F,   // bf16 feats [B*H*W][128]
    const unsigned short* __restrict__ Bt,  // bf16 weight^T [256][1152]
    float* __restrict__ out)                // [32768][256]
{
    __shared__ unsigned short At[128 * 32];   // A tile: [m_local][k_local]
    __shared__ unsigned short Bs[128 * 32];   // B tile: [n_local][k_local]

    const int tid = threadIdx.x;
    const int n0  = blockIdx.x * 128;          // 0 or 128
    const int m0  = blockIdx.y * 128;
    const int bb  = (int)blockIdx.y >> 5;      // batch: 32 m-blocks per batch
    const int iy0 = ((int)blockIdx.y << 1) & 63; // two output rows per block (iy0, iy0+1)

    const int lane = tid & 63, wave = tid >> 6;
    const int wr = (wave >> 1) * 64;           // wave m-offset in tile
    const int wc = (wave & 1) * 64;            // wave n-offset in tile
    const int l15 = lane & 15, quad = lane >> 4;

    v4f acc[4][4];
#pragma unroll
    for (int i = 0; i < 4; i++)
#pragma unroll
        for (int j = 0; j < 4; j++) acc[i][j] = (v4f)(0.0f);

    for (int ks = 0; ks < 36; ++ks) {
        const int tap = ks >> 2;               // 0..8, one tap per 4 K-steps (128/32)
        const int c0  = (ks & 3) << 5;         // channel offset within tap
        const int dy  = tap / 3 - 1;
        const int dx  = tap % 3 - 1;

        __syncthreads();
        // stage A (128 rows x 64B) and B (128 rows x 64B); each thread: 2 chunks of each
#pragma unroll
        for (int it = 0; it < 2; ++it) {
            int e   = tid + (it << 8);         // 0..511
            int row = e >> 2, ch = e & 3;      // 4 x 16B chunks per row
            // A gather
            int iyl = row >> 6, ix = row & 63;
            int ny = ((iy0 + iyl) << 1) + dy;
            int nx = (ix << 1) + dx;
            uint4 av = make_uint4(0u, 0u, 0u, 0u);
            if (((unsigned)ny < 128u) & ((unsigned)nx < 128u)) {
                av = *(const uint4*)(F + ((size_t)(((bb << 14) + (ny << 7) + nx)) << 7)
                                       + c0 + (ch << 3));
            }
            *(uint4*)(At + (row << 5) + (ch << 3)) = av;
            // B (always valid)
            uint4 bv = *(const uint4*)(Bt + (size_t)(n0 + row) * 1152
                                          + (tap << 7) + c0 + (ch << 3));
            *(uint4*)(Bs + (row << 5) + (ch << 3)) = bv;
        }
        __syncthreads();

        v8bf a[4], b[4];
#pragma unroll
        for (int i = 0; i < 4; i++)
            a[i] = *(const v8bf*)(At + ((wr + i * 16 + l15) << 5) + (quad << 3));
#pragma unroll
        for (int j = 0; j < 4; j++)
            b[j] = *(const v8bf*)(Bs + ((wc + j * 16 + l15) << 5) + (quad << 3));
#pragma unroll
        for (int i = 0; i < 4; i++)
#pragma unroll
            for (int j = 0; j < 4; j++)
                acc[i][j] = __builtin_amdgcn_mfma_f32_16x16x32_bf16(a[i], b[j], acc[i][j], 0, 0, 0);
    }

    // epilogue: D layout col = lane&15, row = quad*4 + r
#pragma unroll
    for (int i = 0; i < 4; i++) {
        int mrow = m0 + wr + i * 16 + quad * 4;
#pragma unroll
        for (int j = 0; j < 4; j++) {
            int nn = n0 + wc + j * 16 + l15;
#pragma unroll
            for (int r = 0; r < 4; r++)
                out[(size_t)(mrow + r) * 256 + nn] = acc[i][j][r];
        }
    }
}

// ---- fallback (ws too small): direct fp32 conv, one block per output pixel ----
__global__ void naive_conv_kernel(const float* __restrict__ feats,
                                  const float* __restrict__ w,
                                  float* __restrict__ out) {
    int m = blockIdx.x;        // 0..32767
    int n = threadIdx.x;       // 0..255
    int bb = m >> 12, iy = (m >> 6) & 63, ix = m & 63;
    float acc = 0.f;
    for (int tap = 0; tap < 9; ++tap) {
        int ny = 2 * iy + tap / 3 - 1;
        int nx = 2 * ix + tap % 3 - 1;
        if ((unsigned)ny < 128u && (unsigned)nx < 128u) {
            const float* fr = feats + ((size_t)((bb << 14) + (ny << 7) + nx) << 7);
            const float* wr = w + tap * 32768 + n;
            for (int c = 0; c < 128; ++c) acc += fr[c] * wr[c * 256];
        }
    }
    out[(size_t)m * 256 + n] = acc;
}

extern "C" void kernel_launch(void* const* d_in, const int* in_sizes, int n_in,
                              void* d_out, int out_size, void* d_ws, size_t ws_size,
                              hipStream_t stream) {
    const float* feats  = (const float*)d_in[0];   // 16777216 f32
    const float* weight = (const float*)d_in[1];   // 294912 f32
    const float* alpha  = (const float*)d_in[2];   // 1 f32
    float* out = (float*)d_out;

    coords_alpha_kernel<<<128, 256, 0, stream>>>(out, alpha);

    const size_t NEED = (size_t)16777216 * 2 + (size_t)294912 * 2; // 34.1 MB
    if (ws_size >= NEED) {
        unsigned short* Fb = (unsigned short*)d_ws;
        unsigned short* Bt = Fb + 16777216;
        conv_feats_kernel<<<16384, 256, 0, stream>>>((const float4*)feats, (ushort4*)Fb);
        conv_wt_kernel<<<1152, 256, 0, stream>>>(weight, Bt);
        gemm_conv_kernel<<<dim3(2, 256), 256, 0, stream>>>(Fb, Bt, out);
    } else {
        naive_conv_kernel<<<32768, 256, 0, stream>>>(feats, weight, out);
    }
}

// Round 2
// 145.703 us; speedup vs baseline: 1.1458x; 1.1458x over previous
//
#include <hip/hip_runtime.h>

// B=8, H=W=128, Cin=128, Cout=256, 3x3 stride2 pad1 -> OH=OW=64.
// Implicit GEMM: M=32768, N=256, K=1152 (9 taps x 128).
// d_out (f32): out_feats[32768*256] | out_coords[32768*3] | alpha[1]

#define OUT_FEATS_ELEMS (32768 * 256)
#define OUT_COORDS_OFF  OUT_FEATS_ELEMS
#define ALPHA_OFF       (OUT_FEATS_ELEMS + 32768 * 3)

typedef __bf16 v8bf __attribute__((ext_vector_type(8)));
typedef float  v4f  __attribute__((ext_vector_type(4)));

__device__ __forceinline__ unsigned short f2bf(float f) {
    union { float f; unsigned u; } v; v.f = f;
    return (unsigned short)((v.u + 0x7fffu + ((v.u >> 16) & 1u)) >> 16);
}

#define GLOAD_LDS16(SRC, DST)                                                  \
    __builtin_amdgcn_global_load_lds(                                          \
        (const __attribute__((address_space(1))) void*)(SRC),                  \
        (__attribute__((address_space(3))) void*)(DST), 16, 0, 0)

// ---- prepass 1: feats fp32 -> bf16 (16777216 elems) ----
__global__ void conv_feats_kernel(const float4* __restrict__ f, ushort4* __restrict__ o) {
    int i = blockIdx.x * 256 + threadIdx.x;      // 4194304 threads
    float4 v = f[i];
    ushort4 r;
    r.x = f2bf(v.x); r.y = f2bf(v.y); r.z = f2bf(v.z); r.w = f2bf(v.w);
    o[i] = r;
}

// ---- prepass 2: weight -> pre-swizzled per-(nb,ks) LDS images Bw, + coords + alpha ----
// Bw chunk (nb, ks, row, ch) [16B] = bf16 of w[k = tap*128 + c0 + (ch^(row&7))*8 + j][n = nb*128+row]
__global__ void wt_coords_kernel(const float* __restrict__ w, unsigned short* __restrict__ Bw,
                                 float* __restrict__ out, const float* __restrict__ alpha) {
    int cid = blockIdx.x * 256 + threadIdx.x;    // 0..36863 (144 blocks)
    if (cid < 32768) {                           // coords
        int b = cid >> 12, iy = (cid >> 6) & 63, ix = cid & 63;
        float* c = out + OUT_COORDS_OFF + (size_t)cid * 3;
        c[0] = (float)b; c[1] = (float)iy; c[2] = (float)ix;
        if (cid == 0) out[ALPHA_OFF] = alpha[0];
    }
    int ch  = cid & 7;
    int row = (cid >> 3) & 127;
    int t   = cid >> 10;                         // nb*18 + ks, 0..35
    int nb  = (t >= 18) ? 1 : 0;
    int ks  = t - 18 * nb;
    int tap = ks >> 1;
    int c0  = (ks & 1) << 6;
    int chp = ch ^ (row & 7);
    int n   = (nb << 7) + row;
    int kb  = (tap << 7) + c0 + (chp << 3);
    unsigned short r8[8];
#pragma unroll
    for (int j = 0; j < 8; ++j) r8[j] = f2bf(w[(size_t)(kb + j) * 256 + n]);
    *(uint4*)(Bw + (size_t)cid * 8) = *(const uint4*)r8;
}

// ---- coords for fallback path ----
__global__ void coords_alpha_kernel(float* __restrict__ out, const float* __restrict__ alpha) {
    int i = blockIdx.x * 256 + threadIdx.x;
    int b = i >> 12, iy = (i >> 6) & 63, ix = i & 63;
    float* c = out + OUT_COORDS_OFF + (size_t)i * 3;
    c[0] = (float)b; c[1] = (float)iy; c[2] = (float)ix;
    if (i == 0) out[ALPHA_OFF] = alpha[0];
}

// ---- main implicit GEMM: 128x128 tile, BK=64, global_load_lds staging, XOR-swizzled LDS ----
__global__ __launch_bounds__(256, 2) void gemm_conv_kernel(
    const unsigned short* __restrict__ F,    // bf16 feats [B*128*128][128]
    const unsigned short* __restrict__ Bw,   // pre-swizzled B LDS images
    float* __restrict__ out)                 // [32768][256]
{
    __shared__ unsigned short At[128 * 64];  // [row][k] 128B rows, chunk-swizzled
    __shared__ unsigned short Bs[128 * 64];

    const int tid  = threadIdx.x;
    const int nb   = blockIdx.x;             // 0..1
    const int n0   = nb << 7;
    const int m0   = (int)blockIdx.y << 7;
    const int bb   = (int)blockIdx.y >> 5;
    const int iy0  = ((int)blockIdx.y << 1) & 63;

    const int lane = tid & 63, wave = tid >> 6;
    const int wr   = (wave >> 1) << 6;
    const int wc   = (wave & 1) << 6;
    const int l15  = lane & 15, quad = lane >> 4;

    // staging constants: lane -> (sub-row sr, chunk ch); swizzled source chunk chp
    const int sr   = lane >> 3;              // 0..7
    const int ch   = lane & 7;
    const int chp  = ch ^ sr;                // row&7 == sr for all staging instrs
    const int iy_w = iy0 + (wave >> 1);      // this wave's output row (A rows share iy)
    const int ixb  = ((wave & 1) << 5) + sr; // ix at it=0
    const long rowA0 = (long)bb << 14;

    const unsigned short* bsrc0 = Bw + (((size_t)nb * 18 * 1024) + ((size_t)wave << 8) + lane) * 8;
    unsigned short* adst0 = At + (wave << 11);
    unsigned short* bdst0 = Bs + (wave << 11);

    const int swz0 = (quad ^ (l15 & 7)) << 3;        // t=0 chunk offset (elements)
    const int swz1 = ((4 + quad) ^ (l15 & 7)) << 3;  // t=1

    v4f acc[4][4];
#pragma unroll
    for (int i = 0; i < 4; i++)
#pragma unroll
        for (int j = 0; j < 4; j++) acc[i][j] = (v4f)(0.0f);

    for (int ks = 0; ks < 18; ++ks) {
        const int tap = ks >> 1;
        const int c0  = (ks & 1) << 6;
        const int dy  = tap / 3 - 1;
        const int dx  = tap % 3 - 1;

        const int  ny = (iy_w << 1) + dy;
        const bool vy = (unsigned)ny < 128u;
        const long prow = rowA0 + ((long)ny << 7);

        __syncthreads();
#pragma unroll
        for (int it = 0; it < 4; ++it) {
            int nx = ((ixb + (it << 3)) << 1) + dx;
            bool v = vy & ((unsigned)nx < 128u);
            if (v) {
                const unsigned short* asrc = F + ((prow + nx) << 7) + c0 + (chp << 3);
                GLOAD_LDS16(asrc, adst0 + (it << 9));
            } else {
                uint4 z; z.x = 0u; z.y = 0u; z.z = 0u; z.w = 0u;
                *(uint4*)(At + (((wave << 5) + (it << 3) + sr) << 6) + (ch << 3)) = z;
            }
            GLOAD_LDS16(bsrc0 + (size_t)ks * 8192 + (it << 9), bdst0 + (it << 9));
        }
        __syncthreads();

        v8bf a0[4], a1[4], b0[4], b1[4];
#pragma unroll
        for (int i = 0; i < 4; i++) {
            const unsigned short* p = At + ((wr + (i << 4) + l15) << 6);
            a0[i] = *(const v8bf*)(p + swz0);
            a1[i] = *(const v8bf*)(p + swz1);
        }
#pragma unroll
        for (int j = 0; j < 4; j++) {
            const unsigned short* p = Bs + ((wc + (j << 4) + l15) << 6);
            b0[j] = *(const v8bf*)(p + swz0);
            b1[j] = *(const v8bf*)(p + swz1);
        }
#pragma unroll
        for (int i = 0; i < 4; i++)
#pragma unroll
            for (int j = 0; j < 4; j++) {
                acc[i][j] = __builtin_amdgcn_mfma_f32_16x16x32_bf16(a0[i], b0[j], acc[i][j], 0, 0, 0);
                acc[i][j] = __builtin_amdgcn_mfma_f32_16x16x32_bf16(a1[i], b1[j], acc[i][j], 0, 0, 0);
            }
    }

    // epilogue: D layout col = lane&15, row = quad*4 + r  (verified R0)
#pragma unroll
    for (int i = 0; i < 4; i++) {
        int mrow = m0 + wr + (i << 4) + (quad << 2);
#pragma unroll
        for (int j = 0; j < 4; j++) {
            int nn = n0 + wc + (j << 4) + l15;
#pragma unroll
            for (int r = 0; r < 4; r++)
                out[(size_t)(mrow + r) * 256 + nn] = acc[i][j][r];
        }
    }
}

// ---- fallback: direct fp32 conv ----
__global__ void naive_conv_kernel(const float* __restrict__ feats,
                                  const float* __restrict__ w,
                                  float* __restrict__ out) {
    int m = blockIdx.x;
    int n = threadIdx.x;
    int bb = m >> 12, iy = (m >> 6) & 63, ix = m & 63;
    float acc = 0.f;
    for (int tap = 0; tap < 9; ++tap) {
        int ny = 2 * iy + tap / 3 - 1;
        int nx = 2 * ix + tap % 3 - 1;
        if ((unsigned)ny < 128u && (unsigned)nx < 128u) {
            const float* fr = feats + ((size_t)((bb << 14) + (ny << 7) + nx) << 7);
            const float* wr = w + tap * 32768 + n;
            for (int c = 0; c < 128; ++c) acc += fr[c] * wr[c * 256];
        }
    }
    out[(size_t)m * 256 + n] = acc;
}

extern "C" void kernel_launch(void* const* d_in, const int* in_sizes, int n_in,
                              void* d_out, int out_size, void* d_ws, size_t ws_size,
                              hipStream_t stream) {
    const float* feats  = (const float*)d_in[0];
    const float* weight = (const float*)d_in[1];
    const float* alpha  = (const float*)d_in[2];
    float* out = (float*)d_out;

    const size_t NEED = (size_t)16777216 * 2 + (size_t)2 * 18 * 1024 * 16; // 34,144,256 B
    if (ws_size >= NEED) {
        unsigned short* Fb = (unsigned short*)d_ws;
        unsigned short* Bw = Fb + 16777216;
        conv_feats_kernel<<<16384, 256, 0, stream>>>((const float4*)feats, (ushort4*)Fb);
        wt_coords_kernel<<<144, 256, 0, stream>>>(weight, Bw, out, alpha);
        gemm_conv_kernel<<<dim3(2, 256), 256, 0, stream>>>(Fb, Bw, out);
    } else {
        coords_alpha_kernel<<<128, 256, 0, stream>>>(out, alpha);
        naive_conv_kernel<<<32768, 256, 0, stream>>>(feats, weight, out);
    }
}

// Round 4
// 145.099 us; speedup vs baseline: 1.1506x; 1.0042x over previous
//
#include <hip/hip_runtime.h>

// B=8, H=W=128, Cin=128, Cout=256, 3x3 stride2 pad1 -> OH=OW=64.
// Implicit GEMM: M=32768, N=256, K=1152 (9 taps x 128).
// d_out (f32): out_feats[32768*256] | out_coords[32768*3] | alpha[1]

#define OUT_FEATS_ELEMS (32768 * 256)
#define OUT_COORDS_OFF  OUT_FEATS_ELEMS
#define ALPHA_OFF       (OUT_FEATS_ELEMS + 32768 * 3)

typedef __bf16 v8bf  __attribute__((ext_vector_type(8)));
typedef float  v16f  __attribute__((ext_vector_type(16)));

__device__ __forceinline__ unsigned short f2bf(float f) {
    union { float f; unsigned u; } v; v.f = f;
    return (unsigned short)((v.u + 0x7fffu + ((v.u >> 16) & 1u)) >> 16);
}

#define GLOAD_LDS16(SRC, DST)                                                  \
    __builtin_amdgcn_global_load_lds(                                          \
        (const __attribute__((address_space(1))) void*)(SRC),                  \
        (__attribute__((address_space(3))) void*)(DST), 16, 0, 0)

// ---- prepass 1: feats fp32 -> bf16 (16777216 elems) ----
__global__ void conv_feats_kernel(const float4* __restrict__ f, ushort4* __restrict__ o) {
    int i = blockIdx.x * 256 + threadIdx.x;      // 4194304 threads
    float4 v = f[i];
    ushort4 r;
    r.x = f2bf(v.x); r.y = f2bf(v.y); r.z = f2bf(v.z); r.w = f2bf(v.w);
    o[i] = r;
}

// ---- prepass 2: weight -> pre-swizzled per-(nb,tap) 32KB LDS images, + coords + alpha ----
// Bw[t=nb*9+tap][row 0..127][ch 0..15] (16B chunks):
//   bf16 of w[k = tap*128 + (ch^(row&15))*8 + j][n = nb*128 + row], j=0..7
__global__ void wt_coords_kernel(const float* __restrict__ w, unsigned short* __restrict__ Bw,
                                 float* __restrict__ out, const float* __restrict__ alpha) {
    int cid = blockIdx.x * 256 + threadIdx.x;    // 0..36863 (144 blocks)
    if (cid < 32768) {                           // coords
        int b = cid >> 12, iy = (cid >> 6) & 63, ix = cid & 63;
        float* c = out + OUT_COORDS_OFF + (size_t)cid * 3;
        c[0] = (float)b; c[1] = (float)iy; c[2] = (float)ix;
        if (cid == 0) out[ALPHA_OFF] = alpha[0];
    }
    int ch  = cid & 15;
    int row = (cid >> 4) & 127;
    int t   = cid >> 11;                         // 0..17 = nb*9 + tap
    int nb  = (t >= 9) ? 1 : 0;
    int tap = t - 9 * nb;
    int cl  = ch ^ (row & 15);
    int n   = (nb << 7) + row;
    int kb  = (tap << 7) + (cl << 3);
    unsigned short r8[8];
#pragma unroll
    for (int j = 0; j < 8; ++j) r8[j] = f2bf(w[(size_t)(kb + j) * 256 + n]);
    *(uint4*)(Bw + (size_t)cid * 8) = *(const uint4*)r8;
}

// ---- coords for fallback path ----
__global__ void coords_alpha_kernel(float* __restrict__ out, const float* __restrict__ alpha) {
    int i = blockIdx.x * 256 + threadIdx.x;
    int b = i >> 12, iy = (i >> 6) & 63, ix = i & 63;
    float* c = out + OUT_COORDS_OFF + (size_t)i * 3;
    c[0] = (float)b; c[1] = (float)iy; c[2] = (float)ix;
    if (i == 0) out[ALPHA_OFF] = alpha[0];
}

// ---- main implicit GEMM: 128x128 tile, BK=128 (one tap/step), 32x32x16 MFMA ----
__global__ __launch_bounds__(256, 2) void gemm_conv_kernel(
    const unsigned short* __restrict__ F,    // bf16 feats [B*128*128][128]
    const unsigned short* __restrict__ Bw,   // pre-swizzled B LDS images (18 x 32KB)
    float* __restrict__ out)                 // [32768][256]
{
    __shared__ unsigned short At[128 * 128]; // [row][k] 256B rows, chunk-swizzled (32KB)
    __shared__ unsigned short Bs[128 * 128];

    const int tid  = threadIdx.x;
    const int bid  = blockIdx.x;             // 0..511
    const int my   = bid & 255;
    const int nb   = bid >> 8;               // A-sharing pair: ids differ by 256 (same XCD)
    const int n0   = nb << 7;
    const int m0   = my << 7;
    const int bb   = my >> 5;
    const int iy0  = (my << 1) & 63;

    const int lane = tid & 63, wave = tid >> 6;
    const int wm   = (wave >> 1) << 6;       // wave m-offset (0/64)
    const int wn   = (wave & 1) << 6;        // wave n-offset (0/64)
    const int l31  = lane & 31;
    const int hh   = lane >> 5;              // k-half select
    const int xorm = lane & 15;

    // staging: instr region = wave*8+it covers 4 rows x 256B; lane -> row=region*4+(lane>>4), chunk=lane&15
    const int srow4 = lane >> 4;             // 0..3 sub-row within region
    const long rowA0 = (long)bb << 14;
    // B source: this wave's quarter of the pre-swizzled image (+wave<<12 — the R3 bug was omitting it)
    const unsigned short* bimg = Bw + ((size_t)(nb * 9) << 14) + ((size_t)wave << 12) + ((size_t)lane << 3);
    unsigned short* adst0 = At + (wave << 12);   // wave*8 regions * 512 ushorts
    unsigned short* bdst0 = Bs + (wave << 12);

    v16f acc[2][2];
#pragma unroll
    for (int i = 0; i < 2; i++)
#pragma unroll
        for (int j = 0; j < 2; j++) acc[i][j] = (v16f)(0.0f);

    for (int tap = 0; tap < 9; ++tap) {
        const int dy = tap / 3 - 1;
        const int dx = tap % 3 - 1;

        __syncthreads();
#pragma unroll
        for (int it = 0; it < 8; ++it) {
            const int region = (wave << 3) + it;      // 0..31
            const int row    = (region << 2) + srow4; // 0..127 m-local
            // A gather (one full pixel row of 128 ch; this lane: swizzled 16B chunk)
            const int iyl = row >> 6, ix = row & 63;
            const int ny  = ((iy0 + iyl) << 1) + dy;
            const int nx  = (ix << 1) + dx;
            const int chp = xorm ^ (row & 15);
            if (((unsigned)ny < 128u) & ((unsigned)nx < 128u)) {
                const unsigned short* asrc =
                    F + ((rowA0 + ((long)ny << 7) + nx) << 7) + (chp << 3);
                GLOAD_LDS16(asrc, adst0 + (it << 9));
            } else {
                uint4 z; z.x = 0u; z.y = 0u; z.z = 0u; z.w = 0u;
                *(uint4*)(At + (region << 9) + (lane << 3)) = z;
            }
            // B: sequential DMA from pre-swizzled image (wave offset folded into bimg)
            GLOAD_LDS16(bimg + ((size_t)tap << 14) + (it << 9), bdst0 + (it << 9));
        }
        __syncthreads();

#pragma unroll
        for (int seg = 0; seg < 8; ++seg) {          // K=128 -> 8 x (32x32x16)
            v8bf a[2], b[2];
            const int c = ((seg << 1) + hh) ^ xorm;  // logical chunk ^ (row&15); row&15==xorm
#pragma unroll
            for (int i = 0; i < 2; i++) {
                const int row = wm + (i << 5) + l31;
                a[i] = *(const v8bf*)(At + (row << 7) + (c << 3));
            }
#pragma unroll
            for (int j = 0; j < 2; j++) {
                const int row = wn + (j << 5) + l31;
                b[j] = *(const v8bf*)(Bs + (row << 7) + (c << 3));
            }
#pragma unroll
            for (int i = 0; i < 2; i++)
#pragma unroll
                for (int j = 0; j < 2; j++)
                    acc[i][j] = __builtin_amdgcn_mfma_f32_32x32x16_bf16(a[i], b[j], acc[i][j], 0, 0, 0);
        }
    }

    // epilogue: 32x32 D layout col=lane&31, row=(reg&3)+8*(reg>>2)+4*(lane>>5)  [m74/m101]
#pragma unroll
    for (int i = 0; i < 2; i++)
#pragma unroll
        for (int j = 0; j < 2; j++) {
            const int gcol = n0 + wn + (j << 5) + l31;
#pragma unroll
            for (int r = 0; r < 16; ++r) {
                const int grow = m0 + wm + (i << 5) + (r & 3) + ((r >> 2) << 3) + (hh << 2);
                out[(size_t)grow * 256 + gcol] = acc[i][j][r];
            }
        }
}

// ---- fallback: direct fp32 conv ----
__global__ void naive_conv_kernel(const float* __restrict__ feats,
                                  const float* __restrict__ w,
                                  float* __restrict__ out) {
    int m = blockIdx.x;
    int n = threadIdx.x;
    int bb = m >> 12, iy = (m >> 6) & 63, ix = m & 63;
    float acc = 0.f;
    for (int tap = 0; tap < 9; ++tap) {
        int ny = 2 * iy + tap / 3 - 1;
        int nx = 2 * ix + tap % 3 - 1;
        if ((unsigned)ny < 128u && (unsigned)nx < 128u) {
            const float* fr = feats + ((size_t)((bb << 14) + (ny << 7) + nx) << 7);
            const float* wr = w + tap * 32768 + n;
            for (int c = 0; c < 128; ++c) acc += fr[c] * wr[c * 256];
        }
    }
    out[(size_t)m * 256 + n] = acc;
}

extern "C" void kernel_launch(void* const* d_in, const int* in_sizes, int n_in,
                              void* d_out, int out_size, void* d_ws, size_t ws_size,
                              hipStream_t stream) {
    const float* feats  = (const float*)d_in[0];
    const float* weight = (const float*)d_in[1];
    const float* alpha  = (const float*)d_in[2];
    float* out = (float*)d_out;

    const size_t NEED = (size_t)16777216 * 2 + (size_t)18 * 16384 * 2; // 34,144,256 B
    if (ws_size >= NEED) {
        unsigned short* Fb = (unsigned short*)d_ws;
        unsigned short* Bw = Fb + 16777216;
        conv_feats_kernel<<<16384, 256, 0, stream>>>((const float4*)feats, (ushort4*)Fb);
        wt_coords_kernel<<<144, 256, 0, stream>>>(weight, Bw, out, alpha);
        gemm_conv_kernel<<<512, 256, 0, stream>>>(Fb, Bw, out);
    } else {
        coords_alpha_kernel<<<128, 256, 0, stream>>>(out, alpha);
        naive_conv_kernel<<<32768, 256, 0, stream>>>(feats, weight, out);
    }
}